// Round 12
// baseline (159.362 us; speedup 1.0000x reference)
//
#include <hip/hip_runtime.h>

#define WS   7
#define NH   8
#define HD   32
#define WIN  49
#define HALO 9
#define VHST 36      // sVh row stride in halfs (72B rows, 8B aligned)
#define LST  34      // sLepe row stride in halfs (68B rows, h2-aligned)
#define UPB  4       // independent units (waves) per block

typedef __fp16 h2  __attribute__((ext_vector_type(2)));
typedef __fp16 v4h __attribute__((ext_vector_type(4)));
typedef float  v4f __attribute__((ext_vector_type(4)));

// wave-local LDS fence: this wave's ds ops are drained; no cross-wave coupling.
#define WAVE_LDS_FENCE() asm volatile("s_waitcnt lgkmcnt(0)" ::: "memory")

__device__ __forceinline__ float fexp2(float x) {
    float r;
    asm("v_exp_f32 %0, %1" : "=v"(r) : "v"(x));
    return r;
}

// (256,4): 128-VGPR budget. Min-waves >=5 makes the allocator spill hard
// (r10: VGPR=40, r11: VGPR=48, both +60MB scratch FETCH). r9 proved (256,4)
// allocates naturally (72) with zero spill.
__global__ __launch_bounds__(64 * UPB, 4)
void win_attn_lepe(const float* __restrict__ qkv,
                   const float* __restrict__ lw,
                   const float* __restrict__ lb,
                   float* __restrict__ out,
                   int B, int H, int W, int C)
{
    const int N  = H * W;
    const int Gw = W / WS;
    const int G  = (H / WS) * Gw;

    const int wave = threadIdx.x >> 6;
    const int l    = threadIdx.x & 63;

    const int unit = blockIdx.x * UPB + wave;   // (window)*NH + head
    const int wid  = unit >> 3;
    const int h    = unit & 7;
    const int b    = wid / G;
    const int g    = wid % G;
    const int gy   = g / Gw, gx = g % Gw;
    const int row0 = gy * WS, col0 = gx * WS;
    const int c0   = h * HD;

    const size_t plane = (size_t)B * N * C;
    const float* qb = qkv + (size_t)b * N * C;
    const float* kb = qb + plane;
    const float* vb = qb + 2 * plane;

    const int lr = l & 15;     // A-row / B-col / C-col index
    const int gq = l >> 4;     // k-group

    // sBuf: V halo [81][36] f16 (5832B); sLepe [49][34] f16 (3332B) ALIASES it
    // (safe: all sVh reads precede the aliased writes; pass ranges are fenced/disjoint)
    __shared__ __fp16 sBuf[UPB][HALO * HALO * VHST];
    __shared__ __fp16 sW2 [UPB][16 * 20];            // lepe w as h2: [cp][2t+e]

    __fp16* sVh   = &sBuf[wave][0];
    __fp16* sLepe = &sBuf[wave][0];

    // ---- stage V halo (f16, zero-padded at image boundary) ----
    for (int idx = l; idx < HALO * HALO * 8; idx += 64) {
        int p  = idx >> 3;
        int d4 = (idx & 7) * 4;
        int ry = row0 - 1 + p / HALO, rx = col0 - 1 + p % HALO;
        bool in = (ry >= 0 && ry < H && rx >= 0 && rx < W);
        float4 f = make_float4(0.f, 0.f, 0.f, 0.f);
        if (in) f = *reinterpret_cast<const float4*>(vb + ((size_t)ry * W + rx) * C + c0 + d4);
        h2 a  = __builtin_amdgcn_cvt_pkrtz(f.x, f.y);
        h2 b2 = __builtin_amdgcn_cvt_pkrtz(f.z, f.w);
        v4h v4 = { a.x, a.y, b2.x, b2.y };
        *reinterpret_cast<v4h*>(&sVh[p * VHST + d4]) = v4;
    }
    // ---- stage lepe weights as h2-pairs: sW2[cp*20+2t+e] = lw[(c0+2cp+e)*9+t] ----
    for (int i = l; i < 288; i += 64) {
        int d = i / 9, t = i - d * 9;
        sW2[wave][(d >> 1) * 20 + 2 * t + (d & 1)] = (__fp16)lw[(size_t)(c0 + d) * 9 + t];
    }

    // pixel p (clamped to 48) -> global offset of its channel block
    auto pixoff = [&](int p) -> size_t {
        p = p > 48 ? 48 : p;
        int r = row0 + p / WS, c = col0 + p % WS;
        return ((size_t)r * W + c) * C + c0;
    };

    // 32^-0.5 * log2(e): exp(x) computed as v_exp_f32(x*log2e)
    const float scale = 0.17677669529663687f * 1.4426950408889634f;
    const float ESHIFT = 4.328085122666891f;   // 3*log2e, normalization-invariant

    // ---- Q/K frags loaded EARLY (issue before LePE; HBM latency hides under
    // the LDS-only vf/LePE work below — r8/r9 ordering, T14 style) ----
    v4h qf[4][2];
    #pragma unroll
    for (int m = 0; m < 4; ++m) {
        size_t off = pixoff(16 * m + lr);
        #pragma unroll
        for (int s = 0; s < 2; ++s) {
            float4 f = *reinterpret_cast<const float4*>(qb + off + 16 * s + 4 * gq);
            h2 a  = __builtin_amdgcn_cvt_pkrtz(f.x * scale, f.y * scale);
            h2 b2 = __builtin_amdgcn_cvt_pkrtz(f.z * scale, f.w * scale);
            qf[m][s] = v4h{ a.x, a.y, b2.x, b2.y };
        }
    }
    v4h kf[4][2];
    #pragma unroll
    for (int t = 0; t < 4; ++t) {
        size_t off = pixoff(16 * t + lr);
        #pragma unroll
        for (int s = 0; s < 2; ++s) {
            float4 f = *reinterpret_cast<const float4*>(kb + off + 16 * s + 4 * gq);
            h2 a  = __builtin_amdgcn_cvt_pkrtz(f.x, f.y);
            h2 b2 = __builtin_amdgcn_cvt_pkrtz(f.z, f.w);
            kf[t][s] = v4h{ a.x, a.y, b2.x, b2.y };
        }
    }

    const float bias0 = lb[c0 + lr];
    const float bias1 = lb[c0 + 16 + lr];

    WAVE_LDS_FENCE();   // halo + weight staging visible to this wave

    // ---- V B-frags [s4][n]: V[16s4+4gq+j][16n+lr], read from sVh (f16) ----
    // (must complete before any aliased sLepe write — they do: all reads precede fence A)
    v4h vf[4][2];
    #pragma unroll
    for (int s4 = 0; s4 < 4; ++s4) {
        #pragma unroll
        for (int j = 0; j < 4; ++j) {
            int p  = 16 * s4 + 4 * gq + j;
            int pc = p > 48 ? 48 : p;
            int hp = (pc / WS + 1) * HALO + pc % WS + 1;
            int base = hp * VHST + lr;
            vf[s4][0][j] = sVh[base];
            vf[s4][1][j] = sVh[base + 16];
        }
    }

    // ---- cooperative LePE, 2 register-passes, aliased write-back ----
    h2 w2r[9];
    #pragma unroll
    for (int t = 0; t < 9; ++t)
        w2r[t] = *reinterpret_cast<const h2*>(&sW2[wave][lr * 20 + 2 * t]);

    // pass A: pixels 0..27 (it 0..6). reads halo bytes < 3888; writes [0,1904)
    h2 accA[7];
    #pragma unroll
    for (int it = 0; it < 7; ++it) {
        int pix = it * 4 + gq;
        int wy = pix / WS, wx = pix - (pix / WS) * WS;
        h2 acc = h2{ (__fp16)0.f, (__fp16)0.f };
        #pragma unroll
        for (int dh = 0; dh < 3; ++dh)
            #pragma unroll
            for (int dw = 0; dw < 3; ++dw) {
                h2 v = *reinterpret_cast<const h2*>(
                    &sVh[((wy + dh) * HALO + (wx + dw)) * VHST + 2 * lr]);
                acc += w2r[dh * 3 + dw] * v;
            }
        accA[it] = acc;
    }
    WAVE_LDS_FENCE();   // all sVh reads (vf + pass A) drained
    #pragma unroll
    for (int it = 0; it < 7; ++it)
        *reinterpret_cast<h2*>(&sLepe[(it * 4 + gq) * LST + 2 * lr]) = accA[it];

    // pass B: pixels 28..48 (it 7..12). reads halo bytes >= 2592 (disjoint from A's writes)
    h2 accB[6];
    #pragma unroll
    for (int it = 7; it < 13; ++it) {
        int pix = it * 4 + gq;
        h2 acc = h2{ (__fp16)0.f, (__fp16)0.f };
        if (pix < WIN) {
            int wy = pix / WS, wx = pix - (pix / WS) * WS;
            #pragma unroll
            for (int dh = 0; dh < 3; ++dh)
                #pragma unroll
                for (int dw = 0; dw < 3; ++dw) {
                    h2 v = *reinterpret_cast<const h2*>(
                        &sVh[((wy + dh) * HALO + (wx + dw)) * VHST + 2 * lr]);
                    acc += w2r[dh * 3 + dw] * v;
                }
        }
        accB[it - 7] = acc;
    }
    WAVE_LDS_FENCE();   // pass B reads drained before overwriting [1904,3332)
    #pragma unroll
    for (int it = 7; it < 13; ++it)
        if (it * 4 + gq < WIN)
            *reinterpret_cast<h2*>(&sLepe[(it * 4 + gq) * LST + 2 * lr]) = accB[it - 7];
    WAVE_LDS_FENCE();   // sLepe complete before epilogue reads

    // ---- per query-tile: swapped QK^T (S^T) -> exp2 -> in-lane normalize -> PV ----
    #pragma unroll 1
    for (int mq = 0; mq < 4; ++mq) {
        // sa[tk][r] = S[query=16mq+lr][key=16tk+4gq+r] (pre-scaled by log2e)
        v4f sa[4] = { v4f{0,0,0,0}, v4f{0,0,0,0}, v4f{0,0,0,0}, v4f{0,0,0,0} };
        #pragma unroll
        for (int tk = 0; tk < 4; ++tk)
            #pragma unroll
            for (int s = 0; s < 2; ++s)
                sa[tk] = __builtin_amdgcn_mfma_f32_16x16x16f16(kf[tk][s], qf[mq][s], sa[tk], 0, 0, 0);

        // P~ = 2^(s - 3log2e); keys 0..47 always valid, only (tk=3,gq=0,r=0)=key48 in tail
        float den = 0.f;
        #pragma unroll
        for (int tk = 0; tk < 3; ++tk)
            #pragma unroll
            for (int r = 0; r < 4; ++r) {
                float e = fexp2(sa[tk][r] - ESHIFT);
                sa[tk][r] = e;
                den += e;
            }
        {
            float e0 = (gq == 0) ? fexp2(sa[3][0] - ESHIFT) : 0.f;
            sa[3][0] = e0; sa[3][1] = 0.f; sa[3][2] = 0.f; sa[3][3] = 0.f;
            den += e0;
        }
        den += __shfl_xor(den, 16);
        den += __shfl_xor(den, 32);
        const float inv = __builtin_amdgcn_rcpf(den);

        // normalize in-register, pack to f16 A-fragments: pa[s4][j] = P[lr][16s4+4gq+j]
        v4f oa0 = v4f{0,0,0,0}, oa1 = v4f{0,0,0,0};
        #pragma unroll
        for (int s4 = 0; s4 < 4; ++s4) {
            h2 p01 = __builtin_amdgcn_cvt_pkrtz(sa[s4][0] * inv, sa[s4][1] * inv);
            h2 p23 = __builtin_amdgcn_cvt_pkrtz(sa[s4][2] * inv, sa[s4][3] * inv);
            v4h pa = v4h{ p01.x, p01.y, p23.x, p23.y };
            oa0 = __builtin_amdgcn_mfma_f32_16x16x16f16(pa, vf[s4][0], oa0, 0, 0, 0);
            oa1 = __builtin_amdgcn_mfma_f32_16x16x16f16(pa, vf[s4][1], oa1, 0, 0, 0);
        }

        // epilogue: + lepe + bias, store (pixel p = 16mq+4gq+r, ch = 16n+lr)
        #pragma unroll
        for (int r = 0; r < 4; ++r) {
            int p = 16 * mq + 4 * gq + r;
            if (p < WIN) {
                int rr = row0 + p / WS, cc = col0 + p % WS;
                float* dst = out + ((size_t)b * N + (size_t)rr * W + cc) * C + c0 + lr;
                dst[0]  = oa0[r] + (float)sLepe[p * LST + lr]      + bias0;
                dst[16] = oa1[r] + (float)sLepe[p * LST + 16 + lr] + bias1;
            }
        }
    }
}

extern "C" void kernel_launch(void* const* d_in, const int* in_sizes, int n_in,
                              void* d_out, int out_size, void* d_ws, size_t ws_size,
                              hipStream_t stream) {
    const float* qkv = (const float*)d_in[0];
    const float* lw  = (const float*)d_in[1];
    const float* lb  = (const float*)d_in[2];
    float* out = (float*)d_out;

    const int H = 112, W = 112;
    const int C = in_sizes[2];
    const int N = H * W;
    const int B = in_sizes[0] / (3 * N * C);
    const int G = (H / WS) * (W / WS);

    const int units = B * G * NH;   // 16384, divisible by UPB
    win_attn_lepe<<<units / UPB, 64 * UPB, 0, stream>>>(qkv, lw, lb, out, B, H, W, C);
}

// Round 13
// 129.413 us; speedup vs baseline: 1.2314x; 1.2314x over previous
//
#include <hip/hip_runtime.h>

#define WS   7
#define NH   8
#define HD   32
#define WIN  49
#define HALO 9
#define VHST 36      // sVh row stride in halfs (72B rows, 8B aligned)
#define LTT  36      // sLT (lepe tile) row stride in halfs (72B rows)
#define UPB  4       // independent units (waves) per block

typedef __fp16 h2  __attribute__((ext_vector_type(2)));
typedef __fp16 v4h __attribute__((ext_vector_type(4)));
typedef float  v4f __attribute__((ext_vector_type(4)));

// wave-local LDS fence: this wave's ds ops are drained; no cross-wave coupling.
#define WAVE_LDS_FENCE() asm volatile("s_waitcnt lgkmcnt(0)" ::: "memory")

__device__ __forceinline__ float fexp2(float x) {
    float r;
    asm("v_exp_f32 %0, %1" : "=v"(r) : "v"(x));
    return r;
}

// (256,4): r9 proved this allocates naturally (72 VGPR) with zero spill.
// min-waves >=5 and the aliased 2-pass LePE both forced spills (r10-r12).
__global__ __launch_bounds__(64 * UPB, 4)
void win_attn_lepe(const float* __restrict__ qkv,
                   const float* __restrict__ lw,
                   const float* __restrict__ lb,
                   float* __restrict__ out,
                   int B, int H, int W, int C)
{
    const int N  = H * W;
    const int Gw = W / WS;
    const int G  = (H / WS) * Gw;

    const int wave = threadIdx.x >> 6;
    const int l    = threadIdx.x & 63;

    const int unit = blockIdx.x * UPB + wave;   // (window)*NH + head
    const int wid  = unit >> 3;
    const int h    = unit & 7;
    const int b    = wid / G;
    const int g    = wid % G;
    const int gy   = g / Gw, gx = g % Gw;
    const int row0 = gy * WS, col0 = gx * WS;
    const int c0   = h * HD;

    const size_t plane = (size_t)B * N * C;
    const float* qb = qkv + (size_t)b * N * C;
    const float* kb = qb + plane;
    const float* vb = qb + 2 * plane;

    const int lr = l & 15;     // A-row / B-col / C-col index
    const int gq = l >> 4;     // k-group

    // per-unit LDS: halo 5832B + weights 640B + 16-row lepe tile 1152B = 7624B
    // -> 30.5KB/block -> 5 blocks/CU (vs r9's 4) WITHOUT aliasing hazards.
    __shared__ __fp16 sVh[UPB][HALO * HALO * VHST]; // V halo f16 [81][36]
    __shared__ __fp16 sW2[UPB][16 * 20];            // lepe w as h2: [cp][2t+e]
    __shared__ __fp16 sLT[UPB][16 * LTT];           // lepe tile [16][36], rewritten per mq

    // ---- stage V halo (f16, zero-padded at image boundary) ----
    for (int idx = l; idx < HALO * HALO * 8; idx += 64) {
        int p  = idx >> 3;
        int d4 = (idx & 7) * 4;
        int ry = row0 - 1 + p / HALO, rx = col0 - 1 + p % HALO;
        bool in = (ry >= 0 && ry < H && rx >= 0 && rx < W);
        float4 f = make_float4(0.f, 0.f, 0.f, 0.f);
        if (in) f = *reinterpret_cast<const float4*>(vb + ((size_t)ry * W + rx) * C + c0 + d4);
        h2 a  = __builtin_amdgcn_cvt_pkrtz(f.x, f.y);
        h2 b2 = __builtin_amdgcn_cvt_pkrtz(f.z, f.w);
        v4h v4 = { a.x, a.y, b2.x, b2.y };
        *reinterpret_cast<v4h*>(&sVh[wave][p * VHST + d4]) = v4;
    }
    // ---- stage lepe weights as h2-pairs: sW2[cp*20+2t+e] = lw[(c0+2cp+e)*9+t] ----
    for (int i = l; i < 288; i += 64) {
        int d = i / 9, t = i - d * 9;
        sW2[wave][(d >> 1) * 20 + 2 * t + (d & 1)] = (__fp16)lw[(size_t)(c0 + d) * 9 + t];
    }

    // pixel p (clamped to 48) -> global offset of its channel block
    auto pixoff = [&](int p) -> size_t {
        p = p > 48 ? 48 : p;
        int r = row0 + p / WS, c = col0 + p % WS;
        return ((size_t)r * W + c) * C + c0;
    };

    // 32^-0.5 * log2(e): exp(x) computed as v_exp_f32(x*log2e)
    const float scale = 0.17677669529663687f * 1.4426950408889634f;
    const float ESHIFT = 4.328085122666891f;   // 3*log2e, normalization-invariant

    // ---- Q/K frags loaded EARLY (HBM latency hides under the LDS work below) ----
    v4h qf[4][2];
    #pragma unroll
    for (int m = 0; m < 4; ++m) {
        size_t off = pixoff(16 * m + lr);
        #pragma unroll
        for (int s = 0; s < 2; ++s) {
            float4 f = *reinterpret_cast<const float4*>(qb + off + 16 * s + 4 * gq);
            h2 a  = __builtin_amdgcn_cvt_pkrtz(f.x * scale, f.y * scale);
            h2 b2 = __builtin_amdgcn_cvt_pkrtz(f.z * scale, f.w * scale);
            qf[m][s] = v4h{ a.x, a.y, b2.x, b2.y };
        }
    }
    v4h kf[4][2];
    #pragma unroll
    for (int t = 0; t < 4; ++t) {
        size_t off = pixoff(16 * t + lr);
        #pragma unroll
        for (int s = 0; s < 2; ++s) {
            float4 f = *reinterpret_cast<const float4*>(kb + off + 16 * s + 4 * gq);
            h2 a  = __builtin_amdgcn_cvt_pkrtz(f.x, f.y);
            h2 b2 = __builtin_amdgcn_cvt_pkrtz(f.z, f.w);
            kf[t][s] = v4h{ a.x, a.y, b2.x, b2.y };
        }
    }

    const float bias0 = lb[c0 + lr];
    const float bias1 = lb[c0 + 16 + lr];

    WAVE_LDS_FENCE();   // halo + weight staging visible to this wave

    // ---- V B-frags [s4][n]: V[16s4+4gq+j][16n+lr], read from sVh (f16) ----
    v4h vf[4][2];
    #pragma unroll
    for (int s4 = 0; s4 < 4; ++s4) {
        #pragma unroll
        for (int j = 0; j < 4; ++j) {
            int p  = 16 * s4 + 4 * gq + j;
            int pc = p > 48 ? 48 : p;
            int hp = (pc / WS + 1) * HALO + pc % WS + 1;
            int base = hp * VHST + lr;
            vf[s4][0][j] = sVh[wave][base];
            vf[s4][1][j] = sVh[wave][base + 16];
        }
    }

    // lepe taps for this lane's channel-pair (cp = lr)
    h2 w2r[9];
    #pragma unroll
    for (int t = 0; t < 9; ++t)
        w2r[t] = *reinterpret_cast<const h2*>(&sW2[wave][lr * 20 + 2 * t]);

    // ---- per query-tile: QK^T (swapped) -> in-loop LePE tile -> exp2 -> PV -> store ----
    #pragma unroll 1
    for (int mq = 0; mq < 4; ++mq) {
        // sa[tk][r] = S[query=16mq+lr][key=16tk+4gq+r] (pre-scaled by log2e)
        v4f sa[4] = { v4f{0,0,0,0}, v4f{0,0,0,0}, v4f{0,0,0,0}, v4f{0,0,0,0} };
        #pragma unroll
        for (int tk = 0; tk < 4; ++tk)
            #pragma unroll
            for (int s = 0; s < 2; ++s)
                sa[tk] = __builtin_amdgcn_mfma_f32_16x16x16f16(kf[tk][s], qf[mq][s], sa[tk], 0, 0, 0);

        // orders previous iteration's sLT reads before this iteration's writes
        WAVE_LDS_FENCE();

        // LePE for this 16-pixel tile: lane (lr,gq) computes pixel 16mq+4gq+r,
        // channel pair lr; writes row 4gq+r, halves 2lr..2lr+1. Streaming: acc
        // written immediately (no held-accumulator spill pressure, cf. r10-r12).
        #pragma unroll
        for (int r = 0; r < 4; ++r) {
            int p = 16 * mq + 4 * gq + r;
            if (p < WIN) {
                int wy = p / WS, wx = p - (p / WS) * WS;
                h2 acc = h2{ (__fp16)0.f, (__fp16)0.f };
                #pragma unroll
                for (int dh = 0; dh < 3; ++dh)
                    #pragma unroll
                    for (int dw = 0; dw < 3; ++dw) {
                        h2 v = *reinterpret_cast<const h2*>(
                            &sVh[wave][((wy + dh) * HALO + (wx + dw)) * VHST + 2 * lr]);
                        acc += w2r[dh * 3 + dw] * v;
                    }
                *reinterpret_cast<h2*>(&sLT[wave][(4 * gq + r) * LTT + 2 * lr]) = acc;
            }
        }

        // P~ = 2^(s - 3log2e); keys 0..47 always valid, only (tk=3,gq=0,r=0)=key48 in tail
        // (register-only work: scheduler overlaps it with the LePE DS latency above)
        float den = 0.f;
        #pragma unroll
        for (int tk = 0; tk < 3; ++tk)
            #pragma unroll
            for (int r = 0; r < 4; ++r) {
                float e = fexp2(sa[tk][r] - ESHIFT);
                sa[tk][r] = e;
                den += e;
            }
        {
            float e0 = (gq == 0) ? fexp2(sa[3][0] - ESHIFT) : 0.f;
            sa[3][0] = e0; sa[3][1] = 0.f; sa[3][2] = 0.f; sa[3][3] = 0.f;
            den += e0;
        }
        den += __shfl_xor(den, 16);
        den += __shfl_xor(den, 32);
        const float inv = __builtin_amdgcn_rcpf(den);

        // normalize in-register, pack to f16 A-fragments: pa[s4][j] = P[lr][16s4+4gq+j]
        v4f oa0 = v4f{0,0,0,0}, oa1 = v4f{0,0,0,0};
        #pragma unroll
        for (int s4 = 0; s4 < 4; ++s4) {
            h2 p01 = __builtin_amdgcn_cvt_pkrtz(sa[s4][0] * inv, sa[s4][1] * inv);
            h2 p23 = __builtin_amdgcn_cvt_pkrtz(sa[s4][2] * inv, sa[s4][3] * inv);
            v4h pa = v4h{ p01.x, p01.y, p23.x, p23.y };
            oa0 = __builtin_amdgcn_mfma_f32_16x16x16f16(pa, vf[s4][0], oa0, 0, 0, 0);
            oa1 = __builtin_amdgcn_mfma_f32_16x16x16f16(pa, vf[s4][1], oa1, 0, 0, 0);
        }

        WAVE_LDS_FENCE();   // lepe tile writes drained before epilogue reads

        // epilogue: + lepe + bias, store (pixel p = 16mq+4gq+r, ch = 16n+lr)
        #pragma unroll
        for (int r = 0; r < 4; ++r) {
            int p = 16 * mq + 4 * gq + r;
            if (p < WIN) {
                int rr = row0 + p / WS, cc = col0 + p % WS;
                float* dst = out + ((size_t)b * N + (size_t)rr * W + cc) * C + c0 + lr;
                int lrow = (4 * gq + r) * LTT;
                dst[0]  = oa0[r] + (float)sLT[wave][lrow + lr]      + bias0;
                dst[16] = oa1[r] + (float)sLT[wave][lrow + 16 + lr] + bias1;
            }
        }
    }
}

extern "C" void kernel_launch(void* const* d_in, const int* in_sizes, int n_in,
                              void* d_out, int out_size, void* d_ws, size_t ws_size,
                              hipStream_t stream) {
    const float* qkv = (const float*)d_in[0];
    const float* lw  = (const float*)d_in[1];
    const float* lb  = (const float*)d_in[2];
    float* out = (float*)d_out;

    const int H = 112, W = 112;
    const int C = in_sizes[2];
    const int N = H * W;
    const int B = in_sizes[0] / (3 * N * C);
    const int G = (H / WS) * (W / WS);

    const int units = B * G * NH;   // 16384, divisible by UPB
    win_attn_lepe<<<units / UPB, 64 * UPB, 0, stream>>>(qkv, lw, lb, out, B, H, W, C);
}

// Round 14
// 128.462 us; speedup vs baseline: 1.2405x; 1.0074x over previous
//
#include <hip/hip_runtime.h>

#define WS   7
#define NH   8
#define HD   32
#define WIN  49
#define HALO 9
#define VHST 36      // sVh row stride in halfs (72B rows, 8B aligned)
#define LST  34      // sLepe row stride in halfs (68B rows, h2-aligned)
#define UPB  4       // independent units (waves) per block

typedef __fp16 h2  __attribute__((ext_vector_type(2)));
typedef __fp16 v4h __attribute__((ext_vector_type(4)));
typedef float  v4f __attribute__((ext_vector_type(4)));

// wave-local LDS fence: this wave's ds ops are drained; no cross-wave coupling.
#define WAVE_LDS_FENCE() asm volatile("s_waitcnt lgkmcnt(0)" ::: "memory")

__device__ __forceinline__ float fexp2(float x) {
    float r;
    asm("v_exp_f32 %0, %1" : "=v"(r) : "v"(x));
    return r;
}

// (256,4): r9-proven — natural allocation, zero spill. (>=5 spills: r10-r12.)
__global__ __launch_bounds__(64 * UPB, 4)
void win_attn_lepe(const float* __restrict__ qkv,
                   const float* __restrict__ lw,
                   const float* __restrict__ lb,
                   float* __restrict__ out,
                   int B, int H, int W, int C)
{
    const int N  = H * W;
    const int Gw = W / WS;
    const int G  = (H / WS) * Gw;

    const int wave = threadIdx.x >> 6;
    const int l    = threadIdx.x & 63;

    const int unit = blockIdx.x * UPB + wave;   // (window)*NH + head
    const int wid  = unit >> 3;
    const int h    = unit & 7;
    const int b    = wid / G;
    const int g    = wid % G;
    const int gy   = g / Gw, gx = g % Gw;
    const int row0 = gy * WS, col0 = gx * WS;
    const int c0   = h * HD;

    const size_t plane = (size_t)B * N * C;
    const float* qb = qkv + (size_t)b * N * C;
    const float* kb = qb + plane;
    const float* vb = qb + 2 * plane;

    const int lr = l & 15;     // A-row / B-col / C-col index
    const int gq = l >> 4;     // k-group

    __shared__ __fp16 sVh  [UPB][HALO * HALO * VHST]; // V halo f16 [81][36]
    __shared__ __fp16 sW2  [UPB][16 * 20];            // lepe w as h2: [cp][2t+e]
    __shared__ __fp16 sLepe[UPB][WIN * LST];          // lepe result f16 [49][34]

    // ---- stage V halo (f16, zero-padded at image boundary) ----
    for (int idx = l; idx < HALO * HALO * 8; idx += 64) {
        int p  = idx >> 3;
        int d4 = (idx & 7) * 4;
        int ry = row0 - 1 + p / HALO, rx = col0 - 1 + p % HALO;
        bool in = (ry >= 0 && ry < H && rx >= 0 && rx < W);
        float4 f = make_float4(0.f, 0.f, 0.f, 0.f);
        if (in) f = *reinterpret_cast<const float4*>(vb + ((size_t)ry * W + rx) * C + c0 + d4);
        h2 a  = __builtin_amdgcn_cvt_pkrtz(f.x, f.y);
        h2 b2 = __builtin_amdgcn_cvt_pkrtz(f.z, f.w);
        v4h v4 = { a.x, a.y, b2.x, b2.y };
        *reinterpret_cast<v4h*>(&sVh[wave][p * VHST + d4]) = v4;
    }
    // ---- stage lepe weights as h2-pairs: sW2[cp*20+2t+e] = lw[(c0+2cp+e)*9+t] ----
    for (int i = l; i < 288; i += 64) {
        int d = i / 9, t = i - d * 9;
        sW2[wave][(d >> 1) * 20 + 2 * t + (d & 1)] = (__fp16)lw[(size_t)(c0 + d) * 9 + t];
    }
    WAVE_LDS_FENCE();

    const float bias0 = lb[c0 + lr];
    const float bias1 = lb[c0 + 16 + lr];

    // pixel p (clamped to 48) -> global offset of its channel block
    auto pixoff = [&](int p) -> size_t {
        p = p > 48 ? 48 : p;
        int r = row0 + p / WS, c = col0 + p % WS;
        return ((size_t)r * W + c) * C + c0;
    };

    // 32^-0.5 * log2(e): exp(x) computed as v_exp_f32(x*log2e)
    const float scale = 0.17677669529663687f * 1.4426950408889634f;
    const float ESHIFT = 4.328085122666891f;   // 3*log2e, normalization-invariant

    // ---- Q frags [m][s]: Q[16m+lr][16s+4gq+j], scale folded ----
    v4h qf[4][2];
    #pragma unroll
    for (int m = 0; m < 4; ++m) {
        size_t off = pixoff(16 * m + lr);
        #pragma unroll
        for (int s = 0; s < 2; ++s) {
            float4 f = *reinterpret_cast<const float4*>(qb + off + 16 * s + 4 * gq);
            h2 a  = __builtin_amdgcn_cvt_pkrtz(f.x * scale, f.y * scale);
            h2 b2 = __builtin_amdgcn_cvt_pkrtz(f.z * scale, f.w * scale);
            qf[m][s] = v4h{ a.x, a.y, b2.x, b2.y };
        }
    }
    // ---- K frags [t][s]: K[16t+lr][16s+4gq+j] ----
    v4h kf[4][2];
    #pragma unroll
    for (int t = 0; t < 4; ++t) {
        size_t off = pixoff(16 * t + lr);
        #pragma unroll
        for (int s = 0; s < 2; ++s) {
            float4 f = *reinterpret_cast<const float4*>(kb + off + 16 * s + 4 * gq);
            h2 a  = __builtin_amdgcn_cvt_pkrtz(f.x, f.y);
            h2 b2 = __builtin_amdgcn_cvt_pkrtz(f.z, f.w);
            kf[t][s] = v4h{ a.x, a.y, b2.x, b2.y };
        }
    }

    // ---- V B-frags [s4][n]: V[16s4+4gq+j][16n+lr], read from sVh (f16) ----
    v4h vf[4][2];
    #pragma unroll
    for (int s4 = 0; s4 < 4; ++s4) {
        #pragma unroll
        for (int j = 0; j < 4; ++j) {
            int p  = 16 * s4 + 4 * gq + j;
            int pc = p > 48 ? 48 : p;
            int hp = (pc / WS + 1) * HALO + pc % WS + 1;
            int base = hp * VHST + lr;
            vf[s4][0][j] = sVh[wave][base];
            vf[s4][1][j] = sVh[wave][base + 16];
        }
    }

    // ---- cooperative LePE: sLepe[pix][ch] via packed f16 fma (streaming, r9) ----
    {
        h2 w2r[9];
        #pragma unroll
        for (int t = 0; t < 9; ++t)
            w2r[t] = *reinterpret_cast<const h2*>(&sW2[wave][lr * 20 + 2 * t]);
        #pragma unroll 1
        for (int it = 0; it < 13; ++it) {
            int pix = it * 4 + gq;               // cp = lr
            if (pix < WIN) {
                int wy = pix / WS, wx = pix - (pix / WS) * WS;
                h2 acc = h2{ (__fp16)0.f, (__fp16)0.f };
                #pragma unroll
                for (int dh = 0; dh < 3; ++dh)
                    #pragma unroll
                    for (int dw = 0; dw < 3; ++dw) {
                        h2 v = *reinterpret_cast<const h2*>(
                            &sVh[wave][((wy + dh) * HALO + (wx + dw)) * VHST + 2 * lr]);
                        acc += w2r[dh * 3 + dw] * v;
                    }
                *reinterpret_cast<h2*>(&sLepe[wave][pix * LST + 2 * lr]) = acc;
            }
        }
    }
    WAVE_LDS_FENCE();

    // ---- main loop: TWO independent query-tiles in flight (A=2p, B=2p+1) ----
    // Each tile's chain (QK MFMA -> exp2 -> shfl-reduce -> rcp -> pack -> PV) is
    // long and dependent; duplicated register sets let the scheduler fill one
    // tile's VALU/trans latency with the other's MFMAs (T15 pattern, static idx).
    #pragma unroll 1
    for (int mqp = 0; mqp < 2; ++mqp) {
        const int mqA = 2 * mqp, mqB = 2 * mqp + 1;

        // --- QK^T swapped, both tiles (16 independent MFMAs) ---
        v4f saA[4] = { v4f{0,0,0,0}, v4f{0,0,0,0}, v4f{0,0,0,0}, v4f{0,0,0,0} };
        v4f saB[4] = { v4f{0,0,0,0}, v4f{0,0,0,0}, v4f{0,0,0,0}, v4f{0,0,0,0} };
        #pragma unroll
        for (int tk = 0; tk < 4; ++tk)
            #pragma unroll
            for (int s = 0; s < 2; ++s) {
                saA[tk] = __builtin_amdgcn_mfma_f32_16x16x16f16(kf[tk][s], qf[mqA][s], saA[tk], 0, 0, 0);
                saB[tk] = __builtin_amdgcn_mfma_f32_16x16x16f16(kf[tk][s], qf[mqB][s], saB[tk], 0, 0, 0);
            }

        // --- exp2 + row-sum, both tiles ---
        float denA = 0.f, denB = 0.f;
        #pragma unroll
        for (int tk = 0; tk < 3; ++tk)
            #pragma unroll
            for (int r = 0; r < 4; ++r) {
                float eA = fexp2(saA[tk][r] - ESHIFT);
                float eB = fexp2(saB[tk][r] - ESHIFT);
                saA[tk][r] = eA; denA += eA;
                saB[tk][r] = eB; denB += eB;
            }
        {
            float eA = (gq == 0) ? fexp2(saA[3][0] - ESHIFT) : 0.f;
            float eB = (gq == 0) ? fexp2(saB[3][0] - ESHIFT) : 0.f;
            saA[3][0] = eA; saA[3][1] = 0.f; saA[3][2] = 0.f; saA[3][3] = 0.f;
            saB[3][0] = eB; saB[3][1] = 0.f; saB[3][2] = 0.f; saB[3][3] = 0.f;
            denA += eA; denB += eB;
        }
        denA += __shfl_xor(denA, 16);
        denB += __shfl_xor(denB, 16);
        denA += __shfl_xor(denA, 32);
        denB += __shfl_xor(denB, 32);
        const float invA = __builtin_amdgcn_rcpf(denA);
        const float invB = __builtin_amdgcn_rcpf(denB);

        // --- normalize+pack+PV, both tiles interleaved ---
        v4f oa0A = v4f{0,0,0,0}, oa1A = v4f{0,0,0,0};
        v4f oa0B = v4f{0,0,0,0}, oa1B = v4f{0,0,0,0};
        #pragma unroll
        for (int s4 = 0; s4 < 4; ++s4) {
            h2 pA01 = __builtin_amdgcn_cvt_pkrtz(saA[s4][0] * invA, saA[s4][1] * invA);
            h2 pA23 = __builtin_amdgcn_cvt_pkrtz(saA[s4][2] * invA, saA[s4][3] * invA);
            v4h paA = v4h{ pA01.x, pA01.y, pA23.x, pA23.y };
            h2 pB01 = __builtin_amdgcn_cvt_pkrtz(saB[s4][0] * invB, saB[s4][1] * invB);
            h2 pB23 = __builtin_amdgcn_cvt_pkrtz(saB[s4][2] * invB, saB[s4][3] * invB);
            v4h paB = v4h{ pB01.x, pB01.y, pB23.x, pB23.y };
            oa0A = __builtin_amdgcn_mfma_f32_16x16x16f16(paA, vf[s4][0], oa0A, 0, 0, 0);
            oa0B = __builtin_amdgcn_mfma_f32_16x16x16f16(paB, vf[s4][0], oa0B, 0, 0, 0);
            oa1A = __builtin_amdgcn_mfma_f32_16x16x16f16(paA, vf[s4][1], oa1A, 0, 0, 0);
            oa1B = __builtin_amdgcn_mfma_f32_16x16x16f16(paB, vf[s4][1], oa1B, 0, 0, 0);
        }

        // --- epilogue, both tiles ---
        #pragma unroll
        for (int r = 0; r < 4; ++r) {
            int pA = 16 * mqA + 4 * gq + r;
            if (pA < WIN) {
                int rr = row0 + pA / WS, cc = col0 + pA % WS;
                float* dst = out + ((size_t)b * N + (size_t)rr * W + cc) * C + c0 + lr;
                dst[0]  = oa0A[r] + (float)sLepe[wave][pA * LST + lr]      + bias0;
                dst[16] = oa1A[r] + (float)sLepe[wave][pA * LST + 16 + lr] + bias1;
            }
            int pB = 16 * mqB + 4 * gq + r;
            if (pB < WIN) {
                int rr = row0 + pB / WS, cc = col0 + pB % WS;
                float* dst = out + ((size_t)b * N + (size_t)rr * W + cc) * C + c0 + lr;
                dst[0]  = oa0B[r] + (float)sLepe[wave][pB * LST + lr]      + bias0;
                dst[16] = oa1B[r] + (float)sLepe[wave][pB * LST + 16 + lr] + bias1;
            }
        }
    }
}

extern "C" void kernel_launch(void* const* d_in, const int* in_sizes, int n_in,
                              void* d_out, int out_size, void* d_ws, size_t ws_size,
                              hipStream_t stream) {
    const float* qkv = (const float*)d_in[0];
    const float* lw  = (const float*)d_in[1];
    const float* lb  = (const float*)d_in[2];
    float* out = (float*)d_out;

    const int H = 112, W = 112;
    const int C = in_sizes[2];
    const int N = H * W;
    const int B = in_sizes[0] / (3 * N * C);
    const int G = (H / WS) * (W / WS);

    const int units = B * G * NH;   // 16384, divisible by UPB
    win_attn_lepe<<<units / UPB, 64 * UPB, 0, stream>>>(qkv, lw, lb, out, B, H, W, C);
}

// Round 15
// 126.453 us; speedup vs baseline: 1.2602x; 1.0159x over previous
//
#include <hip/hip_runtime.h>

#define WS   7
#define NH   8
#define HD   32
#define WIN  49
#define HALO 9
#define VHST 36      // sVh row stride in halfs (72B rows, 8B aligned)
#define LST  34      // sLepe row stride in halfs (68B rows, h2-aligned)
#define UPB  4       // independent units (waves) per block

typedef __fp16 h2  __attribute__((ext_vector_type(2)));
typedef __fp16 v4h __attribute__((ext_vector_type(4)));
typedef float  v4f __attribute__((ext_vector_type(4)));

// wave-local LDS fence: this wave's ds ops are drained; no cross-wave coupling.
#define WAVE_LDS_FENCE() asm volatile("s_waitcnt lgkmcnt(0)" ::: "memory")

__device__ __forceinline__ float fexp2(float x) {
    float r;
    asm("v_exp_f32 %0, %1" : "=v"(r) : "v"(x));
    return r;
}

// (256,4): natural allocation (72 VGPR), zero spill — proven best (r9, 126.4us).
// min-waves >=5 forces spills (r10-r12); aliasing/in-loop-LePE/2-tile-ILP all
// failed to beat this structure (r10-r14).
__global__ __launch_bounds__(64 * UPB, 4)
void win_attn_lepe(const float* __restrict__ qkv,
                   const float* __restrict__ lw,
                   const float* __restrict__ lb,
                   float* __restrict__ out,
                   int B, int H, int W, int C)
{
    const int N  = H * W;
    const int Gw = W / WS;
    const int G  = (H / WS) * Gw;

    const int wave = threadIdx.x >> 6;
    const int l    = threadIdx.x & 63;

    const int unit = blockIdx.x * UPB + wave;   // (window)*NH + head
    const int wid  = unit >> 3;
    const int h    = unit & 7;
    const int b    = wid / G;
    const int g    = wid % G;
    const int gy   = g / Gw, gx = g % Gw;
    const int row0 = gy * WS, col0 = gx * WS;
    const int c0   = h * HD;

    const size_t plane = (size_t)B * N * C;
    const float* qb = qkv + (size_t)b * N * C;
    const float* kb = qb + plane;
    const float* vb = qb + 2 * plane;

    const int lr = l & 15;     // A-row / B-col / C-col index
    const int gq = l >> 4;     // k-group

    __shared__ __fp16 sVh  [UPB][HALO * HALO * VHST]; // V halo f16 [81][36]
    __shared__ __fp16 sW2  [UPB][16 * 20];            // lepe w as h2: [cp][2t+e]
    __shared__ __fp16 sLepe[UPB][WIN * LST];          // lepe result f16 [49][34]

    // ---- stage V halo (f16, zero-padded at image boundary) ----
    for (int idx = l; idx < HALO * HALO * 8; idx += 64) {
        int p  = idx >> 3;
        int d4 = (idx & 7) * 4;
        int ry = row0 - 1 + p / HALO, rx = col0 - 1 + p % HALO;
        bool in = (ry >= 0 && ry < H && rx >= 0 && rx < W);
        float4 f = make_float4(0.f, 0.f, 0.f, 0.f);
        if (in) f = *reinterpret_cast<const float4*>(vb + ((size_t)ry * W + rx) * C + c0 + d4);
        h2 a  = __builtin_amdgcn_cvt_pkrtz(f.x, f.y);
        h2 b2 = __builtin_amdgcn_cvt_pkrtz(f.z, f.w);
        v4h v4 = { a.x, a.y, b2.x, b2.y };
        *reinterpret_cast<v4h*>(&sVh[wave][p * VHST + d4]) = v4;
    }
    // ---- stage lepe weights as h2-pairs: sW2[cp*20+2t+e] = lw[(c0+2cp+e)*9+t] ----
    for (int i = l; i < 288; i += 64) {
        int d = i / 9, t = i - d * 9;
        sW2[wave][(d >> 1) * 20 + 2 * t + (d & 1)] = (__fp16)lw[(size_t)(c0 + d) * 9 + t];
    }
    WAVE_LDS_FENCE();

    const float bias0 = lb[c0 + lr];
    const float bias1 = lb[c0 + 16 + lr];

    // pixel p (clamped to 48) -> global offset of its channel block
    auto pixoff = [&](int p) -> size_t {
        p = p > 48 ? 48 : p;
        int r = row0 + p / WS, c = col0 + p % WS;
        return ((size_t)r * W + c) * C + c0;
    };

    // 32^-0.5 * log2(e): exp(x) computed as v_exp_f32(x*log2e)
    const float scale = 0.17677669529663687f * 1.4426950408889634f;
    const float ESHIFT = 4.328085122666891f;   // 3*log2e, normalization-invariant

    // ---- Q frags [m][s]: Q[16m+lr][16s+4gq+j], scale folded ----
    v4h qf[4][2];
    #pragma unroll
    for (int m = 0; m < 4; ++m) {
        size_t off = pixoff(16 * m + lr);
        #pragma unroll
        for (int s = 0; s < 2; ++s) {
            float4 f = *reinterpret_cast<const float4*>(qb + off + 16 * s + 4 * gq);
            h2 a  = __builtin_amdgcn_cvt_pkrtz(f.x * scale, f.y * scale);
            h2 b2 = __builtin_amdgcn_cvt_pkrtz(f.z * scale, f.w * scale);
            qf[m][s] = v4h{ a.x, a.y, b2.x, b2.y };
        }
    }
    // ---- K frags [t][s]: K[16t+lr][16s+4gq+j] ----
    v4h kf[4][2];
    #pragma unroll
    for (int t = 0; t < 4; ++t) {
        size_t off = pixoff(16 * t + lr);
        #pragma unroll
        for (int s = 0; s < 2; ++s) {
            float4 f = *reinterpret_cast<const float4*>(kb + off + 16 * s + 4 * gq);
            h2 a  = __builtin_amdgcn_cvt_pkrtz(f.x, f.y);
            h2 b2 = __builtin_amdgcn_cvt_pkrtz(f.z, f.w);
            kf[t][s] = v4h{ a.x, a.y, b2.x, b2.y };
        }
    }

    // ---- V B-frags [s4][n]: V[16s4+4gq+j][16n+lr], read from sVh (f16) ----
    v4h vf[4][2];
    #pragma unroll
    for (int s4 = 0; s4 < 4; ++s4) {
        #pragma unroll
        for (int j = 0; j < 4; ++j) {
            int p  = 16 * s4 + 4 * gq + j;
            int pc = p > 48 ? 48 : p;
            int hp = (pc / WS + 1) * HALO + pc % WS + 1;
            int base = hp * VHST + lr;
            vf[s4][0][j] = sVh[wave][base];
            vf[s4][1][j] = sVh[wave][base + 16];
        }
    }

    // ---- cooperative LePE: sLepe[pix][ch] via packed f16 fma ----
    {
        h2 w2r[9];
        #pragma unroll
        for (int t = 0; t < 9; ++t)
            w2r[t] = *reinterpret_cast<const h2*>(&sW2[wave][lr * 20 + 2 * t]);
        #pragma unroll 1
        for (int it = 0; it < 13; ++it) {
            int pix = it * 4 + gq;               // cp = lr
            if (pix < WIN) {
                int wy = pix / WS, wx = pix - (pix / WS) * WS;
                h2 acc = h2{ (__fp16)0.f, (__fp16)0.f };
                #pragma unroll
                for (int dh = 0; dh < 3; ++dh)
                    #pragma unroll
                    for (int dw = 0; dw < 3; ++dw) {
                        h2 v = *reinterpret_cast<const h2*>(
                            &sVh[wave][((wy + dh) * HALO + (wx + dw)) * VHST + 2 * lr]);
                        acc += w2r[dh * 3 + dw] * v;
                    }
                *reinterpret_cast<h2*>(&sLepe[wave][pix * LST + 2 * lr]) = acc;
            }
        }
    }
    WAVE_LDS_FENCE();

    // ---- per query-tile: swapped QK^T (S^T) -> exp2 -> in-lane normalize -> PV ----
    // No LDS bounce, no barriers: P is born in the PV A-fragment layout.
    #pragma unroll 1
    for (int mq = 0; mq < 4; ++mq) {
        // sa[tk][r] = S[query=16mq+lr][key=16tk+4gq+r] (pre-scaled by log2e)
        v4f sa[4] = { v4f{0,0,0,0}, v4f{0,0,0,0}, v4f{0,0,0,0}, v4f{0,0,0,0} };
        #pragma unroll
        for (int tk = 0; tk < 4; ++tk)
            #pragma unroll
            for (int s = 0; s < 2; ++s)
                sa[tk] = __builtin_amdgcn_mfma_f32_16x16x16f16(kf[tk][s], qf[mq][s], sa[tk], 0, 0, 0);

        // P~ = 2^(s - 3log2e); keys 0..47 always valid, only (tk=3,gq=0,r=0)=key48 in tail
        float den = 0.f;
        #pragma unroll
        for (int tk = 0; tk < 3; ++tk)
            #pragma unroll
            for (int r = 0; r < 4; ++r) {
                float e = fexp2(sa[tk][r] - ESHIFT);
                sa[tk][r] = e;
                den += e;
            }
        {
            float e0 = (gq == 0) ? fexp2(sa[3][0] - ESHIFT) : 0.f;
            sa[3][0] = e0; sa[3][1] = 0.f; sa[3][2] = 0.f; sa[3][3] = 0.f;
            den += e0;
        }
        den += __shfl_xor(den, 16);
        den += __shfl_xor(den, 32);
        const float inv = __builtin_amdgcn_rcpf(den);

        // normalize in-register, pack to f16 A-fragments: pa[s4][j] = P[lr][16s4+4gq+j]
        v4f oa0 = v4f{0,0,0,0}, oa1 = v4f{0,0,0,0};
        #pragma unroll
        for (int s4 = 0; s4 < 4; ++s4) {
            h2 p01 = __builtin_amdgcn_cvt_pkrtz(sa[s4][0] * inv, sa[s4][1] * inv);
            h2 p23 = __builtin_amdgcn_cvt_pkrtz(sa[s4][2] * inv, sa[s4][3] * inv);
            v4h pa = v4h{ p01.x, p01.y, p23.x, p23.y };
            oa0 = __builtin_amdgcn_mfma_f32_16x16x16f16(pa, vf[s4][0], oa0, 0, 0, 0);
            oa1 = __builtin_amdgcn_mfma_f32_16x16x16f16(pa, vf[s4][1], oa1, 0, 0, 0);
        }

        // epilogue: + lepe + bias, store (pixel p = 16mq+4gq+r, ch = 16n+lr)
        #pragma unroll
        for (int r = 0; r < 4; ++r) {
            int p = 16 * mq + 4 * gq + r;
            if (p < WIN) {
                int rr = row0 + p / WS, cc = col0 + p % WS;
                float* dst = out + ((size_t)b * N + (size_t)rr * W + cc) * C + c0 + lr;
                dst[0]  = oa0[r] + (float)sLepe[wave][p * LST + lr]      + bias0;
                dst[16] = oa1[r] + (float)sLepe[wave][p * LST + 16 + lr] + bias1;
            }
        }
    }
}

extern "C" void kernel_launch(void* const* d_in, const int* in_sizes, int n_in,
                              void* d_out, int out_size, void* d_ws, size_t ws_size,
                              hipStream_t stream) {
    const float* qkv = (const float*)d_in[0];
    const float* lw  = (const float*)d_in[1];
    const float* lb  = (const float*)d_in[2];
    float* out = (float*)d_out;

    const int H = 112, W = 112;
    const int C = in_sizes[2];
    const int N = H * W;
    const int B = in_sizes[0] / (3 * N * C);
    const int G = (H / WS) * (W / WS);

    const int units = B * G * NH;   // 16384, divisible by UPB
    win_attn_lepe<<<units / UPB, 64 * UPB, 0, stream>>>(qkv, lw, lb, out, B, H, W, C);
}